// Round 4
// baseline (211.554 us; speedup 1.0000x reference)
//
#include <hip/hip_runtime.h>
#include <hip/hip_bf16.h>

typedef __bf16 bf16x8 __attribute__((ext_vector_type(8)));
typedef __bf16 bf16x4 __attribute__((ext_vector_type(4)));
typedef float f32x4 __attribute__((ext_vector_type(4)));

#define SLEN 2048
#define NHEADS 16
#define HDIM 64

// ---------------- prep: cast hidden -> bf16; transpose+cast Wqkv, Wo ----------------
// blocks 0..4095: cast (1M float4); 4096..7167: Wqkv^T; 7168..8191: Wo^T
__global__ __launch_bounds__(256) void prep(const float* __restrict__ hidden,
                                            const float* __restrict__ Wqkv,
                                            const float* __restrict__ Wo,
                                            __bf16* __restrict__ A1,
                                            __bf16* __restrict__ Wt,
                                            __bf16* __restrict__ Wot) {
    int b = blockIdx.x;
    if (b < 4096) {
        int i = b * 256 + threadIdx.x;
        float4 v = reinterpret_cast<const float4*>(hidden)[i];
        bf16x4 o = { (__bf16)v.x, (__bf16)v.y, (__bf16)v.z, (__bf16)v.w };
        reinterpret_cast<bf16x4*>(A1)[i] = o;
    } else {
        __shared__ float tile[32][33];
        const float* W; __bf16* Dst; int N, bx, by;
        if (b < 7168) { int bb = b - 4096; W = Wqkv; Dst = Wt;  N = 3072; bx = bb % 96; by = bb / 96; }
        else          { int bb = b - 7168; W = Wo;   Dst = Wot; N = 1024; bx = bb % 32; by = bb / 32; }
        int tx = threadIdx.x & 31, ty = threadIdx.x >> 5;
        int n0 = bx * 32, k0 = by * 32;
        #pragma unroll
        for (int i = ty; i < 32; i += 8)
            tile[i][tx] = W[(size_t)(k0 + i) * N + n0 + tx];
        __syncthreads();
        #pragma unroll
        for (int i = ty; i < 32; i += 8)
            Dst[(size_t)(n0 + i) * 1024 + k0 + tx] = (__bf16)tile[tx][i];
    }
}

// ---------------- GEMM: C[M][N] = A[M][K] @ Bt[N][K]^T  (bf16 in, fp32 acc) ---------
// R1-exact main loop: register-prefetch staging, padded-40 LDS, no swizzle, no rope.
// epi==0: Cf[row][col] = acc + bias[col]  (fp32); epi==1: split Q/K/V bf16 [B][H][S][D]
template <int TN>
__global__ __launch_bounds__(256) void gemm_bt(const __bf16* __restrict__ A,
                                               const __bf16* __restrict__ Bt,
                                               const float* __restrict__ bias,
                                               float* __restrict__ Cf,
                                               __bf16* __restrict__ Cq,
                                               __bf16* __restrict__ Ck,
                                               __bf16* __restrict__ Cv,
                                               int M, int N, int K, int epi) {
    constexpr int JN = TN / 32;   // n-frags per wave
    __shared__ __align__(16) __bf16 As[128 * 40];
    __shared__ __align__(16) __bf16 Bs[TN * 40];

    int nb = N / TN;
    int bx = blockIdx.x % nb;
    int by = blockIdx.x / nb;
    int row0 = by * 128, col0 = bx * TN;

    int tid = threadIdx.x;
    int wave = tid >> 6, lane = tid & 63;
    int quad = lane >> 4, lrow = lane & 15;
    int wm = wave >> 1, wn = wave & 1;

    int r1 = tid >> 2;
    int kk = (tid & 3) * 8;
    const __bf16* Aptr = A + (size_t)(row0 + r1) * K + kk;
    const __bf16* Bptr = Bt + (size_t)(col0 + r1) * K + kk;

    f32x4 acc[4][JN];
    f32x4 zero = {0.f, 0.f, 0.f, 0.f};
    #pragma unroll
    for (int i = 0; i < 4; i++)
        #pragma unroll
        for (int j = 0; j < JN; j++) acc[i][j] = zero;

    for (int k0 = 0; k0 < K; k0 += 32) {
        bf16x8 a0 = *reinterpret_cast<const bf16x8*>(Aptr + k0);
        bf16x8 a1 = *reinterpret_cast<const bf16x8*>(Aptr + (size_t)64 * K + k0);
        bf16x8 b0 = *reinterpret_cast<const bf16x8*>(Bptr + k0);
        bf16x8 b1;
        if (TN == 128) b1 = *reinterpret_cast<const bf16x8*>(Bptr + (size_t)64 * K + k0);
        __syncthreads();
        *reinterpret_cast<bf16x8*>(&As[r1 * 40 + kk]) = a0;
        *reinterpret_cast<bf16x8*>(&As[(r1 + 64) * 40 + kk]) = a1;
        *reinterpret_cast<bf16x8*>(&Bs[r1 * 40 + kk]) = b0;
        if (TN == 128) *reinterpret_cast<bf16x8*>(&Bs[(r1 + 64) * 40 + kk]) = b1;
        __syncthreads();

        bf16x8 af[4], bfr[JN];
        #pragma unroll
        for (int i = 0; i < 4; i++)
            af[i] = *reinterpret_cast<const bf16x8*>(&As[(wm * 64 + i * 16 + lrow) * 40 + quad * 8]);
        #pragma unroll
        for (int j = 0; j < JN; j++)
            bfr[j] = *reinterpret_cast<const bf16x8*>(&Bs[(wn * (TN / 2) + j * 16 + lrow) * 40 + quad * 8]);
        #pragma unroll
        for (int i = 0; i < 4; i++)
            #pragma unroll
            for (int j = 0; j < JN; j++)
                acc[i][j] = __builtin_amdgcn_mfma_f32_16x16x32_bf16(af[i], bfr[j], acc[i][j], 0, 0, 0);
    }

    int part = col0 >> 10;          // block-uniform
    #pragma unroll
    for (int i = 0; i < 4; i++) {
        int rowb = row0 + wm * 64 + i * 16 + quad * 4;
        #pragma unroll
        for (int j = 0; j < JN; j++) {
            int col = col0 + wn * (TN / 2) + j * 16 + lrow;
            float bsv = bias[col];
            #pragma unroll
            for (int r = 0; r < 4; r++) {
                int row = rowb + r;
                float v = acc[i][j][r] + bsv;
                if (epi == 0) {
                    Cf[(size_t)row * N + col] = v;
                } else {
                    int h = (col >> 6) & 15;
                    int d = col & 63;
                    int b = row >> 11;
                    int s = row & 2047;
                    __bf16* dst = (part == 0) ? Cq : ((part == 1) ? Ck : Cv);
                    dst[((size_t)(b * NHEADS + h) * SLEN + s) * HDIM + d] = (__bf16)v;
                }
            }
        }
    }
}

// ---- apply rope to an 8-elem fragment (4 complete pairs in-lane, no shuffles) ----
// a = {c0,s0,c1,s1}, b = {c2,s2,c3,s3} for the 4 pairs.
__device__ __forceinline__ bf16x8 rope8(bf16x8 v, f32x4 a, f32x4 b) {
    bf16x8 o;
    float e, od;
    e = (float)v[0]; od = (float)v[1];
    o[0] = (__bf16)(e * a[0] - od * a[1]); o[1] = (__bf16)(od * a[0] + e * a[1]);
    e = (float)v[2]; od = (float)v[3];
    o[2] = (__bf16)(e * a[2] - od * a[3]); o[3] = (__bf16)(od * a[2] + e * a[3]);
    e = (float)v[4]; od = (float)v[5];
    o[4] = (__bf16)(e * b[0] - od * b[1]); o[5] = (__bf16)(od * b[0] + e * b[1]);
    e = (float)v[6]; od = (float)v[7];
    o[6] = (__bf16)(e * b[2] - od * b[3]); o[7] = (__bf16)(od * b[2] + e * b[3]);
    return o;
}

// ---------------- windowed attention + fused RoPE on Q/K fragment loads ----------
// grid: BH(32) x qtiles(32); block = 4 waves; wave owns 16 queries. No loop barriers.
__global__ __launch_bounds__(256) void attn_kernel(const __bf16* __restrict__ Q,
                                                   const __bf16* __restrict__ K,
                                                   const __bf16* __restrict__ V,
                                                   const float* __restrict__ rope,
                                                   __bf16* __restrict__ O) {
    __shared__ __align__(16) __bf16 Vt[64][328];     // V^T for the block's 320-key union
    __shared__ __align__(16) __bf16 Pl[4][16][40];   // per-wave P roundtrip

    int qt = blockIdx.x & 31;
    int bh = blockIdx.x >> 5;
    int q0 = qt * 64;
    int kbase0 = q0 - 128;
    const __bf16* Qbh = Q + (size_t)bh * SLEN * HDIM;
    const __bf16* Kbh = K + (size_t)bh * SLEN * HDIM;
    const __bf16* Vbh = V + (size_t)bh * SLEN * HDIM;

    int tid = threadIdx.x;
    int wave = tid >> 6, lane = tid & 63;
    int quad = lane >> 4, lrow = lane & 15;
    int wq0 = q0 + wave * 16;

    // ---- stage V^T once: wave handles d-slice [wave*16, wave*16+16), 64 keys/iter
    {
        int dchunk = wave * 16;
        #pragma unroll
        for (int k = 0; k < 5; k++) {
            int off = k * 64 + lane;                 // 0..319
            int krow = kbase0 + off;
            krow = min(max(krow, 0), SLEN - 1);      // clamp: masked later
            const __bf16* vp = Vbh + (size_t)krow * HDIM + dchunk;
            bf16x8 v0 = *reinterpret_cast<const bf16x8*>(vp);
            bf16x8 v1 = *reinterpret_cast<const bf16x8*>(vp + 8);
            #pragma unroll
            for (int i = 0; i < 8; i++) {
                Vt[dchunk + i][off] = v0[i];
                Vt[dchunk + 8 + i][off] = v1[i];
            }
        }
    }

    // Q B-fragments (loop-invariant) with fused rope: lane holds Q[wq0+lrow][quad*8+j]
    int posq = (wq0 + lrow) & 255;
    const float* rq = rope + (size_t)posq * 64;      // row: 32 (c,s) pairs
    f32x4 qc0a = *reinterpret_cast<const f32x4*>(rq + quad * 8);
    f32x4 qc0b = *reinterpret_cast<const f32x4*>(rq + quad * 8 + 4);
    f32x4 qc1a = *reinterpret_cast<const f32x4*>(rq + 32 + quad * 8);
    f32x4 qc1b = *reinterpret_cast<const f32x4*>(rq + 32 + quad * 8 + 4);
    bf16x8 qb0 = rope8(*reinterpret_cast<const bf16x8*>(Qbh + (size_t)(wq0 + lrow) * HDIM + quad * 8),
                       qc0a, qc0b);
    bf16x8 qb1 = rope8(*reinterpret_cast<const bf16x8*>(Qbh + (size_t)(wq0 + lrow) * HDIM + 32 + quad * 8),
                       qc1a, qc1b);

    __syncthreads();   // Vt ready; no barriers after this point

    f32x4 zero = {0.f, 0.f, 0.f, 0.f};
    f32x4 acc[4], acc_l = zero;
    #pragma unroll
    for (int t = 0; t < 4; t++) acc[t] = zero;

    bf16x8 ones = { (__bf16)1.f, (__bf16)1.f, (__bf16)1.f, (__bf16)1.f,
                    (__bf16)1.f, (__bf16)1.f, (__bf16)1.f, (__bf16)1.f };

    // wave-uniform chunk range (32-key chunks, rel. to kbase0)
    int cbeg = wave >> 1;
    if (q0 < 128) { int e = (128 - q0) >> 5; if (e > cbeg) cbeg = e; }
    int cend = (16 * wave + 271) >> 5;
    { int e = (2175 - q0) >> 5; if (e < cend) cend = e; }

    for (int c = cbeg; c <= cend; c++) {
        int kb = kbase0 + c * 32;
        int loc = c * 32;

        // S^T = K . Q^T for two 16-key subtiles (rope fused into K frag loads)
        f32x4 st[2];
        #pragma unroll
        for (int sub = 0; sub < 2; sub++) {
            int kr = kb + sub * 16 + lrow;
            int krc = min(max(kr, 0), SLEN - 1);
            const __bf16* kp = Kbh + (size_t)krc * HDIM;
            const float* rk = rope + (size_t)(krc & 255) * 64;
            f32x4 kc0a = *reinterpret_cast<const f32x4*>(rk + quad * 8);
            f32x4 kc0b = *reinterpret_cast<const f32x4*>(rk + quad * 8 + 4);
            f32x4 kc1a = *reinterpret_cast<const f32x4*>(rk + 32 + quad * 8);
            f32x4 kc1b = *reinterpret_cast<const f32x4*>(rk + 32 + quad * 8 + 4);
            bf16x8 ka0 = rope8(*reinterpret_cast<const bf16x8*>(kp + quad * 8), kc0a, kc0b);
            bf16x8 ka1 = rope8(*reinterpret_cast<const bf16x8*>(kp + 32 + quad * 8), kc1a, kc1b);
            st[sub] = __builtin_amdgcn_mfma_f32_16x16x32_bf16(ka0, qb0, zero, 0, 0, 0);
            st[sub] = __builtin_amdgcn_mfma_f32_16x16x32_bf16(ka1, qb1, st[sub], 0, 0, 0);
        }

        // mask + exp (no max subtraction: scores bounded), pack 4 keys -> 8B LDS write
        int q = wq0 + lrow;
        #pragma unroll
        for (int sub = 0; sub < 2; sub++) {
            bf16x4 pk;
            #pragma unroll
            for (int r = 0; r < 4; r++) {
                int key = kb + sub * 16 + quad * 4 + r;
                int rel = key - q;
                bool valid = (rel >= -128) && (rel <= 128) && (key >= 0) && (key < SLEN);
                float p = valid ? __expf(st[sub][r] * 0.125f) : 0.0f;
                pk[r] = (__bf16)p;
            }
            *reinterpret_cast<bf16x4*>(&Pl[wave][lrow][sub * 16 + quad * 4]) = pk;
        }
        asm volatile("s_waitcnt lgkmcnt(0)" ::: "memory");  // wave-local P roundtrip

        // P B-fragment, PV as O^T = V^T . P^T, row-sums l via A=ones
        bf16x8 bp = *reinterpret_cast<const bf16x8*>(&Pl[wave][lrow][quad * 8]);
        acc_l = __builtin_amdgcn_mfma_f32_16x16x32_bf16(ones, bp, acc_l, 0, 0, 0);
        #pragma unroll
        for (int t = 0; t < 4; t++) {
            bf16x8 va = *reinterpret_cast<const bf16x8*>(&Vt[t * 16 + lrow][loc + quad * 8]);
            acc[t] = __builtin_amdgcn_mfma_f32_16x16x32_bf16(va, bp, acc[t], 0, 0, 0);
        }
    }

    // epilogue: lane holds O^T[d=t*16+quad*4+r][q=lrow]; l[q] = acc_l[0]
    float inv = 1.0f / acc_l[0];
    int b = bh >> 4, h = bh & 15;
    int q = wq0 + lrow;
    size_t base = ((size_t)b * SLEN + q) * 1024 + h * HDIM;
    #pragma unroll
    for (int t = 0; t < 4; t++) {
        bf16x4 o;
        #pragma unroll
        for (int r = 0; r < 4; r++) o[r] = (__bf16)(acc[t][r] * inv);
        *reinterpret_cast<bf16x4*>(&O[base + t * 16 + quad * 4]) = o;
    }
}

extern "C" void kernel_launch(void* const* d_in, const int* in_sizes, int n_in,
                              void* d_out, int out_size, void* d_ws, size_t ws_size,
                              hipStream_t stream) {
    const float* hidden = (const float*)d_in[0];   // [2,2048,1024]
    const float* Wqkv   = (const float*)d_in[1];   // [1024,3072]
    const float* bqkv   = (const float*)d_in[2];   // [3072]
    const float* Wo     = (const float*)d_in[3];   // [1024,1024]
    const float* bo     = (const float*)d_in[4];   // [1024]
    const float* rope   = (const float*)d_in[5];   // [256,32,2]
    float* out = (float*)d_out;                    // [2,2048,1024] fp32

    char* ws = (char*)d_ws;
    __bf16* A1  = (__bf16*)(ws);                   //  8 MiB: hidden bf16 [4096][1024]
    __bf16* Wt  = (__bf16*)(ws + 8388608);         //  6 MiB: Wqkv^T bf16 [3072][1024]
    __bf16* Wot = (__bf16*)(ws + 14680064);        //  2 MiB: Wo^T bf16 [1024][1024]
    __bf16* Qb  = (__bf16*)(ws + 16777216);        //  8 MiB: Q [B][H][S][64]
    __bf16* Kb  = (__bf16*)(ws + 25165824);        //  8 MiB: K
    __bf16* Vb  = (__bf16*)(ws + 33554432);        //  8 MiB: V
    __bf16* AO  = (__bf16*)(ws + 41943040);        //  8 MiB: attn out [4096][1024]

    // fused prep: cast hidden; transpose Wqkv, Wo
    prep<<<8192, 256, 0, stream>>>(hidden, Wqkv, Wo, A1, Wt, Wot);

    // QKV projection: [4096,1024]@[1024,3072] -> Q/K/V [B][H][S][64] (un-roped)
    gemm_bt<128><<<32 * 24, 256, 0, stream>>>(A1, Wt, bqkv, nullptr, Qb, Kb, Vb,
                                              4096, 3072, 1024, 1);
    // windowed attention (rope fused on Q/K loads) -> AO [4096][1024] bf16
    attn_kernel<<<1024, 256, 0, stream>>>(Qb, Kb, Vb, rope, AO);
    // output projection: [4096,1024]@[1024,1024] + bias -> d_out fp32
    gemm_bt<64><<<32 * 16, 256, 0, stream>>>(AO, Wot, bo, out, nullptr, nullptr, nullptr,
                                             4096, 1024, 1024, 0);
}

// Round 5
// 190.347 us; speedup vs baseline: 1.1114x; 1.1114x over previous
//
#include <hip/hip_runtime.h>
#include <hip/hip_bf16.h>

typedef __bf16 bf16x8 __attribute__((ext_vector_type(8)));
typedef __bf16 bf16x4 __attribute__((ext_vector_type(4)));
typedef float f32x4 __attribute__((ext_vector_type(4)));

#define SLEN 2048
#define NHEADS 16
#define HDIM 64

// ---------------- prep: cast hidden -> bf16; transpose+cast Wqkv, Wo ----------------
// blocks 0..4095: cast (1M float4); 4096..7167: Wqkv^T; 7168..8191: Wo^T
__global__ __launch_bounds__(256) void prep(const float* __restrict__ hidden,
                                            const float* __restrict__ Wqkv,
                                            const float* __restrict__ Wo,
                                            __bf16* __restrict__ A1,
                                            __bf16* __restrict__ Wt,
                                            __bf16* __restrict__ Wot) {
    int b = blockIdx.x;
    if (b < 4096) {
        int i = b * 256 + threadIdx.x;
        float4 v = reinterpret_cast<const float4*>(hidden)[i];
        bf16x4 o = { (__bf16)v.x, (__bf16)v.y, (__bf16)v.z, (__bf16)v.w };
        reinterpret_cast<bf16x4*>(A1)[i] = o;
    } else {
        __shared__ float tile[32][33];
        const float* W; __bf16* Dst; int N, bx, by;
        if (b < 7168) { int bb = b - 4096; W = Wqkv; Dst = Wt;  N = 3072; bx = bb % 96; by = bb / 96; }
        else          { int bb = b - 7168; W = Wo;   Dst = Wot; N = 1024; bx = bb % 32; by = bb / 32; }
        int tx = threadIdx.x & 31, ty = threadIdx.x >> 5;
        int n0 = bx * 32, k0 = by * 32;
        #pragma unroll
        for (int i = ty; i < 32; i += 8)
            tile[i][tx] = W[(size_t)(k0 + i) * N + n0 + tx];
        __syncthreads();
        #pragma unroll
        for (int i = ty; i < 32; i += 8)
            Dst[(size_t)(n0 + i) * 1024 + k0 + tx] = (__bf16)tile[tx][i];
    }
}

// ---------------- GEMM: C[M][N] = A[M][K] @ Bt[N][K]^T  (bf16 in, fp32 acc) ---------
// R1-exact main loop: register-prefetch staging, padded-40 LDS.
// epi==0: Cf[row][col] = acc + bias[col]  (fp32); epi==1: split Q/K/V bf16 [B][H][S][D]
template <int TN>
__global__ __launch_bounds__(256) void gemm_bt(const __bf16* __restrict__ A,
                                               const __bf16* __restrict__ Bt,
                                               const float* __restrict__ bias,
                                               float* __restrict__ Cf,
                                               __bf16* __restrict__ Cq,
                                               __bf16* __restrict__ Ck,
                                               __bf16* __restrict__ Cv,
                                               int M, int N, int K, int epi) {
    constexpr int JN = TN / 32;   // n-frags per wave
    __shared__ __align__(16) __bf16 As[128 * 40];
    __shared__ __align__(16) __bf16 Bs[TN * 40];

    int nb = N / TN;
    int bx = blockIdx.x % nb;
    int by = blockIdx.x / nb;
    int row0 = by * 128, col0 = bx * TN;

    int tid = threadIdx.x;
    int wave = tid >> 6, lane = tid & 63;
    int quad = lane >> 4, lrow = lane & 15;
    int wm = wave >> 1, wn = wave & 1;

    int r1 = tid >> 2;
    int kk = (tid & 3) * 8;
    const __bf16* Aptr = A + (size_t)(row0 + r1) * K + kk;
    const __bf16* Bptr = Bt + (size_t)(col0 + r1) * K + kk;

    f32x4 acc[4][JN];
    f32x4 zero = {0.f, 0.f, 0.f, 0.f};
    #pragma unroll
    for (int i = 0; i < 4; i++)
        #pragma unroll
        for (int j = 0; j < JN; j++) acc[i][j] = zero;

    for (int k0 = 0; k0 < K; k0 += 32) {
        bf16x8 a0 = *reinterpret_cast<const bf16x8*>(Aptr + k0);
        bf16x8 a1 = *reinterpret_cast<const bf16x8*>(Aptr + (size_t)64 * K + k0);
        bf16x8 b0 = *reinterpret_cast<const bf16x8*>(Bptr + k0);
        bf16x8 b1;
        if (TN == 128) b1 = *reinterpret_cast<const bf16x8*>(Bptr + (size_t)64 * K + k0);
        __syncthreads();
        *reinterpret_cast<bf16x8*>(&As[r1 * 40 + kk]) = a0;
        *reinterpret_cast<bf16x8*>(&As[(r1 + 64) * 40 + kk]) = a1;
        *reinterpret_cast<bf16x8*>(&Bs[r1 * 40 + kk]) = b0;
        if (TN == 128) *reinterpret_cast<bf16x8*>(&Bs[(r1 + 64) * 40 + kk]) = b1;
        __syncthreads();

        bf16x8 af[4], bfr[JN];
        #pragma unroll
        for (int i = 0; i < 4; i++)
            af[i] = *reinterpret_cast<const bf16x8*>(&As[(wm * 64 + i * 16 + lrow) * 40 + quad * 8]);
        #pragma unroll
        for (int j = 0; j < JN; j++)
            bfr[j] = *reinterpret_cast<const bf16x8*>(&Bs[(wn * (TN / 2) + j * 16 + lrow) * 40 + quad * 8]);
        #pragma unroll
        for (int i = 0; i < 4; i++)
            #pragma unroll
            for (int j = 0; j < JN; j++)
                acc[i][j] = __builtin_amdgcn_mfma_f32_16x16x32_bf16(af[i], bfr[j], acc[i][j], 0, 0, 0);
    }

    int part = col0 >> 10;          // block-uniform
    #pragma unroll
    for (int i = 0; i < 4; i++) {
        int rowb = row0 + wm * 64 + i * 16 + quad * 4;
        #pragma unroll
        for (int j = 0; j < JN; j++) {
            int col = col0 + wn * (TN / 2) + j * 16 + lrow;
            float bsv = bias[col];
            #pragma unroll
            for (int r = 0; r < 4; r++) {
                int row = rowb + r;
                float v = acc[i][j][r] + bsv;
                if (epi == 0) {
                    Cf[(size_t)row * N + col] = v;
                } else {
                    int h = (col >> 6) & 15;
                    int d = col & 63;
                    int b = row >> 11;
                    int s = row & 2047;
                    __bf16* dst = (part == 0) ? Cq : ((part == 1) ? Ck : Cv);
                    dst[((size_t)(b * NHEADS + h) * SLEN + s) * HDIM + d] = (__bf16)v;
                }
            }
        }
    }
}

// ---------------- RoPE in place on Q,K  [BH][S][64], pos = s % 256 ----------------
__global__ __launch_bounds__(256) void rope_kernel(__bf16* __restrict__ Q,
                                                   __bf16* __restrict__ K,
                                                   const float* __restrict__ rope) {
    int idx = blockIdx.x * 256 + threadIdx.x;  // [0, 32*2048*32)
    int p = idx & 31;
    int s = (idx >> 5) & 2047;
    int bh = idx >> 16;
    size_t off = ((size_t)bh * SLEN + s) * HDIM + 2 * p;
    int pos = s & 255;
    float c = rope[(pos * 32 + p) * 2];
    float sn = rope[(pos * 32 + p) * 2 + 1];
    float q0 = (float)Q[off], q1 = (float)Q[off + 1];
    Q[off]     = (__bf16)(q0 * c - q1 * sn);
    Q[off + 1] = (__bf16)(q1 * c + q0 * sn);
    float k0 = (float)K[off], k1 = (float)K[off + 1];
    K[off]     = (__bf16)(k0 * c - k1 * sn);
    K[off + 1] = (__bf16)(k1 * c + k0 * sn);
}

// ---------------- windowed attention v3 + K-prefetch pipeline ----------------
// grid: BH(32) x qtiles(32); block = 4 waves; wave owns 16 queries. No loop barriers.
// S^T = K.Q^T; P packed to LDS (8B); O^T = V^T.P^T; row-sums via one MFMA with A=ones.
__global__ __launch_bounds__(256) void attn_kernel(const __bf16* __restrict__ Q,
                                                   const __bf16* __restrict__ K,
                                                   const __bf16* __restrict__ V,
                                                   __bf16* __restrict__ O) {
    __shared__ __align__(16) __bf16 Vt[64][328];     // V^T for the block's 320-key union
    __shared__ __align__(16) __bf16 Pl[4][16][40];   // per-wave P roundtrip

    int qt = blockIdx.x & 31;
    int bh = blockIdx.x >> 5;
    int q0 = qt * 64;
    int kbase0 = q0 - 128;
    const __bf16* Qbh = Q + (size_t)bh * SLEN * HDIM;
    const __bf16* Kbh = K + (size_t)bh * SLEN * HDIM;
    const __bf16* Vbh = V + (size_t)bh * SLEN * HDIM;

    int tid = threadIdx.x;
    int wave = tid >> 6, lane = tid & 63;
    int quad = lane >> 4, lrow = lane & 15;
    int wq0 = q0 + wave * 16;

    // ---- stage V^T once: wave handles d-slice [wave*16, wave*16+16), 64 keys/iter
    {
        int dchunk = wave * 16;
        #pragma unroll
        for (int k = 0; k < 5; k++) {
            int off = k * 64 + lane;                 // 0..319
            int krow = kbase0 + off;
            krow = min(max(krow, 0), SLEN - 1);      // clamp: masked later
            const __bf16* vp = Vbh + (size_t)krow * HDIM + dchunk;
            bf16x8 v0 = *reinterpret_cast<const bf16x8*>(vp);
            bf16x8 v1 = *reinterpret_cast<const bf16x8*>(vp + 8);
            #pragma unroll
            for (int i = 0; i < 8; i++) {
                Vt[dchunk + i][off] = v0[i];
                Vt[dchunk + 8 + i][off] = v1[i];
            }
        }
    }

    // Q B-fragments (loop-invariant): lane holds Q[wq0+lrow][quad*8+j]
    bf16x8 qb0 = *reinterpret_cast<const bf16x8*>(Qbh + (size_t)(wq0 + lrow) * HDIM + quad * 8);
    bf16x8 qb1 = *reinterpret_cast<const bf16x8*>(Qbh + (size_t)(wq0 + lrow) * HDIM + 32 + quad * 8);

    __syncthreads();   // Vt ready; no barriers after this point

    f32x4 zero = {0.f, 0.f, 0.f, 0.f};
    f32x4 acc[4], acc_l = zero;
    #pragma unroll
    for (int t = 0; t < 4; t++) acc[t] = zero;

    bf16x8 ones = { (__bf16)1.f, (__bf16)1.f, (__bf16)1.f, (__bf16)1.f,
                    (__bf16)1.f, (__bf16)1.f, (__bf16)1.f, (__bf16)1.f };

    // wave-uniform chunk range (32-key chunks, rel. to kbase0)
    int cbeg = wave >> 1;
    if (q0 < 128) { int e = (128 - q0) >> 5; if (e > cbeg) cbeg = e; }
    int cend = (16 * wave + 271) >> 5;
    { int e = (2175 - q0) >> 5; if (e < cend) cend = e; }

    // K-fragment loader (2 subtiles x 2 halves)
    auto loadK = [&](int c, bf16x8 kf[2][2]) {
        int kb = kbase0 + c * 32;
        #pragma unroll
        for (int sub = 0; sub < 2; sub++) {
            int kr = kb + sub * 16 + lrow;
            int krc = min(max(kr, 0), SLEN - 1);
            const __bf16* kp = Kbh + (size_t)krc * HDIM;
            kf[sub][0] = *reinterpret_cast<const bf16x8*>(kp + quad * 8);
            kf[sub][1] = *reinterpret_cast<const bf16x8*>(kp + 32 + quad * 8);
        }
    };

    bf16x8 ka[2][2];
    loadK(cbeg, ka);

    for (int c = cbeg; c <= cend; c++) {
        // prefetch next chunk's K fragments (latency hidden behind this chunk's compute)
        bf16x8 kn[2][2];
        if (c < cend) loadK(c + 1, kn);

        int kb = kbase0 + c * 32;
        int loc = c * 32;

        // S^T = K . Q^T for two 16-key subtiles
        f32x4 st[2];
        #pragma unroll
        for (int sub = 0; sub < 2; sub++) {
            st[sub] = __builtin_amdgcn_mfma_f32_16x16x32_bf16(ka[sub][0], qb0, zero, 0, 0, 0);
            st[sub] = __builtin_amdgcn_mfma_f32_16x16x32_bf16(ka[sub][1], qb1, st[sub], 0, 0, 0);
        }

        // mask + exp (no max subtraction: scores bounded), pack 4 keys -> 8B LDS write
        int q = wq0 + lrow;
        #pragma unroll
        for (int sub = 0; sub < 2; sub++) {
            bf16x4 pk;
            #pragma unroll
            for (int r = 0; r < 4; r++) {
                int key = kb + sub * 16 + quad * 4 + r;
                int rel = key - q;
                bool valid = (rel >= -128) && (rel <= 128) && (key >= 0) && (key < SLEN);
                float p = valid ? __expf(st[sub][r] * 0.125f) : 0.0f;
                pk[r] = (__bf16)p;
            }
            *reinterpret_cast<bf16x4*>(&Pl[wave][lrow][sub * 16 + quad * 4]) = pk;
        }
        asm volatile("s_waitcnt lgkmcnt(0)" ::: "memory");  // wave-local P roundtrip

        // P B-fragment, PV as O^T = V^T . P^T, row-sums l via A=ones
        bf16x8 bp = *reinterpret_cast<const bf16x8*>(&Pl[wave][lrow][quad * 8]);
        acc_l = __builtin_amdgcn_mfma_f32_16x16x32_bf16(ones, bp, acc_l, 0, 0, 0);
        #pragma unroll
        for (int t = 0; t < 4; t++) {
            bf16x8 va = *reinterpret_cast<const bf16x8*>(&Vt[t * 16 + lrow][loc + quad * 8]);
            acc[t] = __builtin_amdgcn_mfma_f32_16x16x32_bf16(va, bp, acc[t], 0, 0, 0);
        }

        #pragma unroll
        for (int sub = 0; sub < 2; sub++) {
            ka[sub][0] = kn[sub][0];
            ka[sub][1] = kn[sub][1];
        }
    }

    // epilogue: lane holds O^T[d=t*16+quad*4+r][q=lrow]; l[q] = acc_l[0]
    float inv = 1.0f / acc_l[0];
    int b = bh >> 4, h = bh & 15;
    int q = wq0 + lrow;
    size_t base = ((size_t)b * SLEN + q) * 1024 + h * HDIM;
    #pragma unroll
    for (int t = 0; t < 4; t++) {
        bf16x4 o;
        #pragma unroll
        for (int r = 0; r < 4; r++) o[r] = (__bf16)(acc[t][r] * inv);
        *reinterpret_cast<bf16x4*>(&O[base + t * 16 + quad * 4]) = o;
    }
}

extern "C" void kernel_launch(void* const* d_in, const int* in_sizes, int n_in,
                              void* d_out, int out_size, void* d_ws, size_t ws_size,
                              hipStream_t stream) {
    const float* hidden = (const float*)d_in[0];   // [2,2048,1024]
    const float* Wqkv   = (const float*)d_in[1];   // [1024,3072]
    const float* bqkv   = (const float*)d_in[2];   // [3072]
    const float* Wo     = (const float*)d_in[3];   // [1024,1024]
    const float* bo     = (const float*)d_in[4];   // [1024]
    const float* rope   = (const float*)d_in[5];   // [256,32,2]
    float* out = (float*)d_out;                    // [2,2048,1024] fp32

    char* ws = (char*)d_ws;
    __bf16* A1  = (__bf16*)(ws);                   //  8 MiB: hidden bf16 [4096][1024]
    __bf16* Wt  = (__bf16*)(ws + 8388608);         //  6 MiB: Wqkv^T bf16 [3072][1024]
    __bf16* Wot = (__bf16*)(ws + 14680064);        //  2 MiB: Wo^T bf16 [1024][1024]
    __bf16* Qb  = (__bf16*)(ws + 16777216);        //  8 MiB: Q [B][H][S][64]
    __bf16* Kb  = (__bf16*)(ws + 25165824);        //  8 MiB: K
    __bf16* Vb  = (__bf16*)(ws + 33554432);        //  8 MiB: V
    __bf16* AO  = (__bf16*)(ws + 41943040);        //  8 MiB: attn out [4096][1024]

    // fused prep: cast hidden; transpose Wqkv, Wo
    prep<<<8192, 256, 0, stream>>>(hidden, Wqkv, Wo, A1, Wt, Wot);

    // QKV projection: [4096,1024]@[1024,3072] -> Q/K/V [B][H][S][64] (un-roped)
    gemm_bt<128><<<32 * 24, 256, 0, stream>>>(A1, Wt, bqkv, nullptr, Qb, Kb, Vb,
                                              4096, 3072, 1024, 1);
    // RoPE on Q,K in place
    rope_kernel<<<8192, 256, 0, stream>>>(Qb, Kb, rope);
    // windowed attention -> AO [4096][1024] bf16
    attn_kernel<<<1024, 256, 0, stream>>>(Qb, Kb, Vb, AO);
    // output projection: [4096,1024]@[1024,1024] + bias -> d_out fp32
    gemm_bt<64><<<32 * 16, 256, 0, stream>>>(AO, Wot, bo, out, nullptr, nullptr, nullptr,
                                             4096, 1024, 1024, 0);
}